// Round 2
// baseline (165.927 us; speedup 1.0000x reference)
//
#include <hip/hip_runtime.h>

// Density-Aware Chamfer Loss, B=8, N=M=4096, fp32.
// Dedup round: single cross pass with dual (row,col) mins; triangular
// symmetric density pass; exp2-prescaled KDE.

#define NPTS 4096
#define NB   8
#define TS   128            // tile size in points
#define NT   (NPTS/TS)      // 32 tiles per cloud per batch
#define TPB  256

#define CROSS_BLOCKS 1024   // NB * NT * 4 col-quarters
#define DENS_BLOCKS  1024   // NB * 2 clouds * 16 u-pairs * 4 quarters
#define BIGF 3.4e38f

// unpack 8 consecutive xyz points (6 float4) from LDS into register arrays
__device__ __forceinline__ void unpack8(const float4* s4, int base,
                                        float (&X)[8], float (&Y)[8], float (&Z)[8])
{
    float4 A = s4[base+0], B = s4[base+1], C = s4[base+2];
    float4 D = s4[base+3], E = s4[base+4], F = s4[base+5];
    X[0]=A.x; Y[0]=A.y; Z[0]=A.z;  X[1]=A.w; Y[1]=B.x; Z[1]=B.y;
    X[2]=B.z; Y[2]=B.w; Z[2]=C.x;  X[3]=C.y; Y[3]=C.z; Z[3]=C.w;
    X[4]=D.x; Y[4]=D.y; Z[4]=D.z;  X[5]=D.w; Y[5]=E.x; Z[5]=E.y;
    X[6]=E.z; Y[6]=E.w; Z[6]=F.x;  X[7]=F.y; Y[7]=F.z; Z[7]=F.w;
}

__global__ void dacl_init(int* __restrict__ minbase, float* __restrict__ densbase)
{
    const int g = blockIdx.x * 256 + threadIdx.x;   // [0, 65536)
    minbase[g]  = 0x7F800000;                        // +inf bits
    densbase[g] = 0.0f;
}

__global__ __launch_bounds__(TPB) void dacl_pairs(
    const float* __restrict__ pred, const float* __restrict__ gt,
    const float* __restrict__ bwp,  const float* __restrict__ bwg,
    int*   __restrict__ minP2G, int*   __restrict__ minG2P,
    float* __restrict__ densP,  float* __restrict__ densG)
{
    __shared__ float4 sRow4[TS*3/4];   // 96 float4 = 1.5 KB
    __shared__ float4 sCol4[TS*3/4];

    const int tid = threadIdx.x;
    const int ty  = tid & 15;          // lane bits 0..3  -> in-wave shfl reduce
    const int tx  = tid >> 4;          // lane bits 4..5 + wave id
    int bid = blockIdx.x;

    if (bid < CROSS_BLOCKS) {
        // ---------------- cross pass: dual-min over pred(rows) x gt(cols) ----
        const int q  = bid & 3;            // col quarter (8 tiles)
        const int TU = (bid >> 2) & 31;    // row tile
        const int b  = bid >> 7;           // batch

        const float4* rsrc = (const float4*)(pred + ((size_t)b*NPTS + TU*TS)*3);
        if (tid < 96) sRow4[tid] = rsrc[tid];
        __syncthreads();

        float rx[8], ry[8], rz[8];
        unpack8(sRow4, ty*6, rx, ry, rz);

        float rmin[8];
        #pragma unroll
        for (int r = 0; r < 8; ++r) rmin[r] = BIGF;

        for (int s = 0; s < 8; ++s) {
            const int TV = q*8 + s;
            __syncthreads();
            const float4* csrc = (const float4*)(gt + ((size_t)b*NPTS + TV*TS)*3);
            if (tid < 96) sCol4[tid] = csrc[tid];
            __syncthreads();

            float cx[8], cy[8], cz[8];
            unpack8(sCol4, tx*6, cx, cy, cz);

            float cmin[8];
            #pragma unroll
            for (int c = 0; c < 8; ++c) cmin[c] = BIGF;

            #pragma unroll
            for (int r = 0; r < 8; ++r) {
                #pragma unroll
                for (int c = 0; c < 8; ++c) {
                    float dx = rx[r]-cx[c], dy = ry[r]-cy[c], dz = rz[r]-cz[c];
                    float d  = dx*dx; d = fmaf(dy,dy,d); d = fmaf(dz,dz,d);
                    rmin[r] = fminf(rmin[r], d);
                    cmin[c] = fminf(cmin[c], d);
                }
            }
            // col mins: reduce over ty (16 lanes, in-wave), one atomic per col
            #pragma unroll
            for (int c = 0; c < 8; ++c) {
                float v = cmin[c];
                v = fminf(v, __shfl_xor(v, 1, 64));
                v = fminf(v, __shfl_xor(v, 2, 64));
                v = fminf(v, __shfl_xor(v, 4, 64));
                v = fminf(v, __shfl_xor(v, 8, 64));
                if (ty == 0)
                    atomicMin(&minG2P[b*NPTS + TV*TS + tx*8 + c], __float_as_int(v));
            }
        }
        // row mins: partial reduce over tx within wave, then atomic
        #pragma unroll
        for (int r = 0; r < 8; ++r) {
            float v = rmin[r];
            v = fminf(v, __shfl_xor(v, 16, 64));
            v = fminf(v, __shfl_xor(v, 32, 64));
            if ((tx & 3) == 0)
                atomicMin(&minP2G[b*NPTS + TU*TS + ty*8 + r], __float_as_int(v));
        }
    } else {
        // ---------------- density pass: symmetric, triangular tiles ----------
        bid -= CROSS_BLOCKS;
        const int qu = bid & 3;            // step quarter
        const int u  = (bid >> 2) & 15;    // row-tile pair {u, 31-u}
        const int cl = (bid >> 6) & 1;     // cloud
        const int b  = bid >> 7;           // batch

        const float* __restrict__ P = cl ? gt : pred;
        float* __restrict__ D = cl ? densG : densP;
        const float bw = cl ? bwg[0] : bwp[0];
        const float sc = sqrtf(0.5f / (bw*bw*0.6931471805599453f)); // exp2 prescale

        const int n0 = 32 - u;                 // seg A: RT=u, TV=u..31
        const int lo = (qu*33) >> 2;           // 0,8,16,24
        const int hi = ((qu+1)*33) >> 2;       // 8,16,24,33

        float rx[8], ry[8], rz[8], racc[8];
        int curRT = -1;

        for (int s = lo; s < hi; ++s) {
            int RT, TV;
            if (s < n0) { RT = u;    TV = u + s; }
            else        { RT = 31-u; TV = (31-u) + (s - n0); }
            const bool newRT = (RT != curRT);

            __syncthreads();
            if (newRT) {
                if (curRT >= 0) {   // flush finished row tile
                    #pragma unroll
                    for (int r = 0; r < 8; ++r) {
                        float v = racc[r];
                        v += __shfl_xor(v, 16, 64);
                        v += __shfl_xor(v, 32, 64);
                        if ((tx & 3) == 0)
                            atomicAdd(&D[b*NPTS + curRT*TS + ty*8 + r], v);
                    }
                }
                const float4* rsrc = (const float4*)(P + ((size_t)b*NPTS + RT*TS)*3);
                if (tid < 96) {
                    float4 v = rsrc[tid];
                    v.x*=sc; v.y*=sc; v.z*=sc; v.w*=sc;
                    sRow4[tid] = v;
                }
            }
            const float4* csrc = (const float4*)(P + ((size_t)b*NPTS + TV*TS)*3);
            if (tid < 96) {
                float4 v = csrc[tid];
                v.x*=sc; v.y*=sc; v.z*=sc; v.w*=sc;
                sCol4[tid] = v;
            }
            __syncthreads();

            if (newRT) {
                unpack8(sRow4, ty*6, rx, ry, rz);
                #pragma unroll
                for (int r = 0; r < 8; ++r) racc[r] = 0.0f;
                curRT = RT;
            }
            float cx[8], cy[8], cz[8];
            unpack8(sCol4, tx*6, cx, cy, cz);

            if (RT == TV) {
                // diagonal tile: full 8x8, row accumulation only (incl. self)
                #pragma unroll
                for (int r = 0; r < 8; ++r) {
                    #pragma unroll
                    for (int c = 0; c < 8; ++c) {
                        float dx = rx[r]-cx[c], dy = ry[r]-cy[c], dz = rz[r]-cz[c];
                        float t = -dx*dx; t = fmaf(dy,-dy,t); t = fmaf(dz,-dz,t);
                        racc[r] += __builtin_amdgcn_exp2f(t);
                    }
                }
            } else {
                float cacc[8];
                #pragma unroll
                for (int c = 0; c < 8; ++c) cacc[c] = 0.0f;
                #pragma unroll
                for (int r = 0; r < 8; ++r) {
                    #pragma unroll
                    for (int c = 0; c < 8; ++c) {
                        float dx = rx[r]-cx[c], dy = ry[r]-cy[c], dz = rz[r]-cz[c];
                        float t = -dx*dx; t = fmaf(dy,-dy,t); t = fmaf(dz,-dz,t);
                        float k = __builtin_amdgcn_exp2f(t);
                        racc[r] += k;
                        cacc[c] += k;
                    }
                }
                #pragma unroll
                for (int c = 0; c < 8; ++c) {
                    float v = cacc[c];
                    v += __shfl_xor(v, 1, 64);
                    v += __shfl_xor(v, 2, 64);
                    v += __shfl_xor(v, 4, 64);
                    v += __shfl_xor(v, 8, 64);
                    if (ty == 0)
                        atomicAdd(&D[b*NPTS + TV*TS + tx*8 + c], v);
                }
            }
        }
        if (curRT >= 0) {   // final flush
            #pragma unroll
            for (int r = 0; r < 8; ++r) {
                float v = racc[r];
                v += __shfl_xor(v, 16, 64);
                v += __shfl_xor(v, 32, 64);
                if ((tx & 3) == 0)
                    atomicAdd(&D[b*NPTS + curRT*TS + ty*8 + r], v);
            }
        }
    }
}

__global__ __launch_bounds__(256) void dacl_combine(
    const int* __restrict__ minP2G, const int* __restrict__ minG2P,
    const float* __restrict__ densP, const float* __restrict__ densG,
    float* __restrict__ bsum)
{
    const int g   = blockIdx.x * 256 + threadIdx.x;  // [0, 65536)
    const int dir = g >> 15;
    const int idx = g & 32767;
    const float m  = __int_as_float(dir ? minG2P[idx] : minP2G[idx]);
    const float dn =                 dir ? densG[idx]  : densP[idx];
    float val = m / (dn * (1.0f/4095.0f) + 1e-6f) * (1.0f/32768.0f);

    #pragma unroll
    for (int off = 32; off; off >>= 1) val += __shfl_down(val, off);
    __shared__ float sm[4];
    const int lane = threadIdx.x & 63, wid = threadIdx.x >> 6;
    if (lane == 0) sm[wid] = val;
    __syncthreads();
    if (threadIdx.x == 0) bsum[blockIdx.x] = (sm[0] + sm[1]) + (sm[2] + sm[3]);
}

__global__ __launch_bounds__(256) void dacl_final(
    const float* __restrict__ bsum, float* __restrict__ out)
{
    float v = bsum[threadIdx.x];
    #pragma unroll
    for (int off = 32; off; off >>= 1) v += __shfl_down(v, off);
    __shared__ float sm[4];
    const int lane = threadIdx.x & 63, wid = threadIdx.x >> 6;
    if (lane == 0) sm[wid] = v;
    __syncthreads();
    if (threadIdx.x == 0) out[0] = (sm[0] + sm[1]) + (sm[2] + sm[3]);
}

extern "C" void kernel_launch(void* const* d_in, const int* in_sizes, int n_in,
                              void* d_out, int out_size, void* d_ws, size_t ws_size,
                              hipStream_t stream)
{
    const float* pred = (const float*)d_in[0];
    const float* gt   = (const float*)d_in[1];
    const float* bwp  = (const float*)d_in[2];
    const float* bwg  = (const float*)d_in[3];

    int*   minP2G = (int*)d_ws;                       // [NB*NPTS]
    int*   minG2P = minP2G + NB*NPTS;                 // [NB*NPTS]
    float* densP  = (float*)(minG2P + NB*NPTS);       // [NB*NPTS]
    float* densG  = densP + NB*NPTS;                  // [NB*NPTS]
    float* bsum   = densG + NB*NPTS;                  // [256]

    dacl_init<<<(2*NB*NPTS)/256, 256, 0, stream>>>(minP2G, densP);
    dacl_pairs<<<CROSS_BLOCKS + DENS_BLOCKS, TPB, 0, stream>>>(
        pred, gt, bwp, bwg, minP2G, minG2P, densP, densG);
    dacl_combine<<<(2*NB*NPTS)/256, 256, 0, stream>>>(minP2G, minG2P, densP, densG, bsum);
    dacl_final<<<1, 256, 0, stream>>>(bsum, (float*)d_out);
}

// Round 3
// 132.031 us; speedup vs baseline: 1.2567x; 1.2567x over previous
//
#include <hip/hip_runtime.h>

// Density-Aware Chamfer Loss, B=8, N=M=4096, fp32.
// Round 3: dedup'd pair enumeration (cross once w/ dual mins; symmetric
// density triangular) + stage-everything-once barrier-free inner loops +
// dot-product form with hoisted per-row/per-col norms.

#define NPTS 4096
#define NB   8
#define TS   128
#define TPB  256
#define BIGF 3.4e38f

// unpack 8 consecutive xyz points (6 float4) from LDS into register arrays
__device__ __forceinline__ void unpack8(const float4* s4, int base,
                                        float (&X)[8], float (&Y)[8], float (&Z)[8])
{
    float4 A = s4[base+0], B = s4[base+1], C = s4[base+2];
    float4 D = s4[base+3], E = s4[base+4], F = s4[base+5];
    X[0]=A.x; Y[0]=A.y; Z[0]=A.z;  X[1]=A.w; Y[1]=B.x; Z[1]=B.y;
    X[2]=B.z; Y[2]=B.w; Z[2]=C.x;  X[3]=C.y; Y[3]=C.z; Z[3]=C.w;
    X[4]=D.x; Y[4]=D.y; Z[4]=D.z;  X[5]=D.w; Y[5]=E.x; Z[5]=E.y;
    X[6]=E.z; Y[6]=E.w; Z[6]=F.x;  X[7]=F.y; Y[7]=F.z; Z[7]=F.w;
}

__global__ void dacl_init(int* __restrict__ minbase, float* __restrict__ densbase)
{
    const int g = blockIdx.x * 256 + threadIdx.x;   // [0, 65536)
    minbase[g]  = 0x7F800000;                        // +inf bits
    densbase[g] = 0.0f;
}

__global__ __launch_bounds__(TPB) void dacl_pairs(
    const float* __restrict__ pred, const float* __restrict__ gt,
    const float* __restrict__ bwp,  const float* __restrict__ bwg,
    int*   __restrict__ minP2G, int*   __restrict__ minG2P,
    float* __restrict__ densP,  float* __restrict__ densG)
{
    __shared__ float4 sMem[96*2 + 96*9];   // 16.9 KB, partitioned per branch

    const int tid = threadIdx.x;
    const int ty  = tid & 15;          // lane bits 0..3
    const int tx  = tid >> 4;          // lane bits 4..5 + wave id
    const int which = blockIdx.x & 1;  // interleave cross/dens across CUs
    const int bid   = blockIdx.x >> 1;

    if (which == 0) {
        // ======== cross pass: pred rows x gt cols, dual mins, 1 barrier ======
        const int q  = bid & 3;            // col quarter (8 tiles, contiguous)
        const int TU = (bid >> 2) & 31;    // row tile
        const int b  = bid >> 7;           // batch

        float4* sRow = sMem;               // 96
        float4* sCol = sMem + 96;          // 768

        const float4* rsrc = (const float4*)(pred + ((size_t)b*NPTS + TU*TS)*3);
        const float4* csrc = (const float4*)(gt   + ((size_t)b*NPTS + q*8*TS)*3);
        if (tid < 96) sRow[tid] = rsrc[tid];
        #pragma unroll
        for (int i = 0; i < 3; ++i) sCol[tid + i*TPB] = csrc[tid + i*TPB];
        __syncthreads();

        float rx[8], ry[8], rz[8], rr[8], rmin[8];
        unpack8(sRow, ty*6, rx, ry, rz);
        #pragma unroll
        for (int r = 0; r < 8; ++r) {
            rr[r] = fmaf(rx[r],rx[r], fmaf(ry[r],ry[r], rz[r]*rz[r]));
            rmin[r] = BIGF;
        }

        for (int s = 0; s < 8; ++s) {
            float cx[8], cy[8], cz[8], cmin[8];
            unpack8(sCol, s*96 + tx*6, cx, cy, cz);

            #pragma unroll
            for (int c = 0; c < 8; ++c) {
                const float ax = -2.0f*cx[c], ay = -2.0f*cy[c], az = -2.0f*cz[c];
                const float cc = fmaf(cx[c],cx[c], fmaf(cy[c],cy[c], cz[c]*cz[c]));
                float cm = BIGF;
                #pragma unroll
                for (int r = 0; r < 8; ++r) {
                    float t = fmaf(ax, rx[r], cc);
                    t = fmaf(ay, ry[r], t);
                    t = fmaf(az, rz[r], t);
                    const float d = t + rr[r];
                    rmin[r] = fminf(rmin[r], d);
                    cm      = fminf(cm, d);
                }
                cmin[c] = cm;
            }
            // col mins: reduce over ty (in-wave), one atomic per col per wave-grp
            #pragma unroll
            for (int c = 0; c < 8; ++c) {
                float v = cmin[c];
                v = fminf(v, __shfl_xor(v, 1, 64));
                v = fminf(v, __shfl_xor(v, 2, 64));
                v = fminf(v, __shfl_xor(v, 4, 64));
                v = fminf(v, __shfl_xor(v, 8, 64));
                if (ty == 0)
                    atomicMin(&minG2P[b*NPTS + (q*8+s)*TS + tx*8 + c],
                              __float_as_int(v));
            }
        }
        #pragma unroll
        for (int r = 0; r < 8; ++r) {
            float v = rmin[r];
            v = fminf(v, __shfl_xor(v, 16, 64));
            v = fminf(v, __shfl_xor(v, 32, 64));
            if ((tx & 3) == 0)
                atomicMin(&minP2G[b*NPTS + TU*TS + ty*8 + r], __float_as_int(v));
        }
    } else {
        // ======== density pass: symmetric triangular, 1 barrier ==============
        const int qu = bid & 3;            // step quarter
        const int u  = (bid >> 2) & 15;    // row-tile pair {u, 31-u}
        const int cl = (bid >> 6) & 1;     // cloud
        const int b  = bid >> 7;           // batch

        const float* __restrict__ P = cl ? gt : pred;
        float* __restrict__ D = cl ? densG : densP;
        const float bw = cl ? bwg[0] : bwp[0];
        const float sc = sqrtf(0.5f / (bw*bw*0.6931471805599453f)); // exp2 prescale

        const int n0  = 32 - u;                // seg A: RT=u, TV=u+s, s<n0
        const int lo  = (qu*33) >> 2;          // 0,8,16,24
        const int hi  = ((qu+1)*33) >> 2;      // 8,16,24,33
        const int nst = hi - lo;               // 8 or 9
        int nA = n0 - lo; if (nA > nst) nA = nst; if (nA < 0) nA = 0;

        float4* sRowA = sMem;                  // 96 (tile u, prescaled)
        float4* sRowB = sMem + 96;             // 96 (tile 31-u, prescaled)
        float4* sCol  = sMem + 192;            // nst*96 (step col tiles)

        const float* base = P + (size_t)b*NPTS*3;
        if (tid < 96) {
            float4 v = ((const float4*)(base + (size_t)u*TS*3))[tid];
            v.x*=sc; v.y*=sc; v.z*=sc; v.w*=sc;  sRowA[tid] = v;
        } else if (tid >= 128 && tid < 224) {
            const int i = tid - 128;
            float4 v = ((const float4*)(base + (size_t)(31-u)*TS*3))[i];
            v.x*=sc; v.y*=sc; v.z*=sc; v.w*=sc;  sRowB[i] = v;
        }
        {   // seg-A col tiles: contiguous range starting at tile (u+lo)
            const float4* srcA = (const float4*)(base + (size_t)(u+lo)*TS*3);
            for (int i = tid; i < nA*96; i += TPB) {
                float4 v = srcA[i];
                v.x*=sc; v.y*=sc; v.z*=sc; v.w*=sc;  sCol[i] = v;
            }
            // seg-B col tiles: contiguous range
            const int sB0 = lo > n0 ? lo : n0;
            const float4* srcB = (const float4*)(base + (size_t)((31-u)+(sB0-n0))*TS*3);
            const int nBf4 = (nst - nA)*96;
            for (int i = tid; i < nBf4; i += TPB) {
                float4 v = srcB[i];
                v.x*=sc; v.y*=sc; v.z*=sc; v.w*=sc;  sCol[nA*96 + i] = v;
            }
        }
        __syncthreads();

        float rx[8], ry[8], rz[8], rr[8], racc[8];
        int curRT = -1;

        auto flushRows = [&](int RTf) {
            #pragma unroll
            for (int r = 0; r < 8; ++r) {
                float v = racc[r];
                v += __shfl_xor(v, 16, 64);
                v += __shfl_xor(v, 32, 64);
                if ((tx & 3) == 0)
                    atomicAdd(&D[b*NPTS + RTf*TS + ty*8 + r], v);
            }
        };

        for (int t = 0; t < nst; ++t) {
            const int s = lo + t;
            int RT, TV;
            if (s < n0) { RT = u;    TV = u + s; }
            else        { RT = 31-u; TV = (31-u) + (s - n0); }

            if (RT != curRT) {
                if (curRT >= 0) flushRows(curRT);
                unpack8(RT == u ? sRowA : sRowB, ty*6, rx, ry, rz);
                #pragma unroll
                for (int r = 0; r < 8; ++r) {
                    rr[r] = fmaf(rx[r],rx[r], fmaf(ry[r],ry[r], rz[r]*rz[r]));
                    racc[r] = 0.0f;
                }
                curRT = RT;
            }

            float cx[8], cy[8], cz[8];
            unpack8(sCol, t*96 + tx*6, cx, cy, cz);

            if (RT == TV) {
                // diagonal: row accumulation only (self included, exp2(0)=1)
                #pragma unroll
                for (int c = 0; c < 8; ++c) {
                    const float ax = 2.0f*cx[c], ay = 2.0f*cy[c], az = 2.0f*cz[c];
                    const float ccn = -fmaf(cx[c],cx[c], fmaf(cy[c],cy[c], cz[c]*cz[c]));
                    #pragma unroll
                    for (int r = 0; r < 8; ++r) {
                        float e = fmaf(ax, rx[r], ccn);
                        e = fmaf(ay, ry[r], e);
                        e = fmaf(az, rz[r], e);
                        racc[r] += __builtin_amdgcn_exp2f(e - rr[r]);
                    }
                }
            } else {
                float cacc[8];
                #pragma unroll
                for (int c = 0; c < 8; ++c) {
                    const float ax = 2.0f*cx[c], ay = 2.0f*cy[c], az = 2.0f*cz[c];
                    const float ccn = -fmaf(cx[c],cx[c], fmaf(cy[c],cy[c], cz[c]*cz[c]));
                    float ca = 0.0f;
                    #pragma unroll
                    for (int r = 0; r < 8; ++r) {
                        float e = fmaf(ax, rx[r], ccn);
                        e = fmaf(ay, ry[r], e);
                        e = fmaf(az, rz[r], e);
                        const float k = __builtin_amdgcn_exp2f(e - rr[r]);
                        racc[r] += k;
                        ca      += k;
                    }
                    cacc[c] = ca;
                }
                #pragma unroll
                for (int c = 0; c < 8; ++c) {
                    float v = cacc[c];
                    v += __shfl_xor(v, 1, 64);
                    v += __shfl_xor(v, 2, 64);
                    v += __shfl_xor(v, 4, 64);
                    v += __shfl_xor(v, 8, 64);
                    if (ty == 0)
                        atomicAdd(&D[b*NPTS + TV*TS + tx*8 + c], v);
                }
            }
        }
        if (curRT >= 0) flushRows(curRT);
    }
}

__global__ __launch_bounds__(256) void dacl_combine(
    const int* __restrict__ minP2G, const int* __restrict__ minG2P,
    const float* __restrict__ densP, const float* __restrict__ densG,
    float* __restrict__ bsum)
{
    const int g   = blockIdx.x * 256 + threadIdx.x;  // [0, 65536)
    const int dir = g >> 15;
    const int idx = g & 32767;
    const float m  = fmaxf(__int_as_float(dir ? minG2P[idx] : minP2G[idx]), 0.0f);
    const float dn =                       dir ? densG[idx]  : densP[idx];
    float val = m / (dn * (1.0f/4095.0f) + 1e-6f) * (1.0f/32768.0f);

    #pragma unroll
    for (int off = 32; off; off >>= 1) val += __shfl_down(val, off);
    __shared__ float sm[4];
    const int lane = threadIdx.x & 63, wid = threadIdx.x >> 6;
    if (lane == 0) sm[wid] = val;
    __syncthreads();
    if (threadIdx.x == 0) bsum[blockIdx.x] = (sm[0] + sm[1]) + (sm[2] + sm[3]);
}

__global__ __launch_bounds__(256) void dacl_final(
    const float* __restrict__ bsum, float* __restrict__ out)
{
    float v = bsum[threadIdx.x];
    #pragma unroll
    for (int off = 32; off; off >>= 1) v += __shfl_down(v, off);
    __shared__ float sm[4];
    const int lane = threadIdx.x & 63, wid = threadIdx.x >> 6;
    if (lane == 0) sm[wid] = v;
    __syncthreads();
    if (threadIdx.x == 0) out[0] = (sm[0] + sm[1]) + (sm[2] + sm[3]);
}

extern "C" void kernel_launch(void* const* d_in, const int* in_sizes, int n_in,
                              void* d_out, int out_size, void* d_ws, size_t ws_size,
                              hipStream_t stream)
{
    const float* pred = (const float*)d_in[0];
    const float* gt   = (const float*)d_in[1];
    const float* bwp  = (const float*)d_in[2];
    const float* bwg  = (const float*)d_in[3];

    int*   minP2G = (int*)d_ws;                       // [NB*NPTS]
    int*   minG2P = minP2G + NB*NPTS;                 // [NB*NPTS]
    float* densP  = (float*)(minG2P + NB*NPTS);       // [NB*NPTS]
    float* densG  = densP + NB*NPTS;                  // [NB*NPTS]
    float* bsum   = densG + NB*NPTS;                  // [256]

    dacl_init<<<(2*NB*NPTS)/256, 256, 0, stream>>>(minP2G, densP);
    dacl_pairs<<<2048, TPB, 0, stream>>>(pred, gt, bwp, bwg,
                                         minP2G, minG2P, densP, densG);
    dacl_combine<<<(2*NB*NPTS)/256, 256, 0, stream>>>(minP2G, minG2P, densP, densG, bsum);
    dacl_final<<<1, 256, 0, stream>>>(bsum, (float*)d_out);
}

// Round 4
// 81.676 us; speedup vs baseline: 2.0315x; 1.6165x over previous
//
#include <hip/hip_runtime.h>

// Density-Aware Chamfer Loss, B=8, N=M=4096, fp32.
// Round 4: full-work clean loops (no atomics, no in-loop cross-lane reductions,
// exclusive output ownership -> plain stores) + minimal per-pair op counts:
//   cross:   3 FMA + 1 min   (|r|^2 folded out of the loop)
//   density: 3 FMA + 1 add + exp2 + 1 add   (exp2-prescaled coords)

#define NPTS 4096
#define NB   8
#define TS   128
#define TPB  256
#define BIGF 3.4e38f

// unpack 8 consecutive xyz points (6 float4) from LDS into register arrays
__device__ __forceinline__ void unpack8(const float4* s4, int base,
                                        float (&X)[8], float (&Y)[8], float (&Z)[8])
{
    float4 A = s4[base+0], B = s4[base+1], C = s4[base+2];
    float4 D = s4[base+3], E = s4[base+4], F = s4[base+5];
    X[0]=A.x; Y[0]=A.y; Z[0]=A.z;  X[1]=A.w; Y[1]=B.x; Z[1]=B.y;
    X[2]=B.z; Y[2]=B.w; Z[2]=C.x;  X[3]=C.y; Y[3]=C.z; Z[3]=C.w;
    X[4]=D.x; Y[4]=D.y; Z[4]=D.z;  X[5]=D.w; Y[5]=E.x; Z[5]=E.y;
    X[6]=E.z; Y[6]=E.w; Z[6]=F.x;  X[7]=F.y; Y[7]=F.z; Z[7]=F.w;
}

// kinds: 0 cross P->G, 1 cross G->P, 2/3 dens P half0/1, 4/5 dens G half0/1
__global__ __launch_bounds__(TPB) void dacl_pairs(
    const float* __restrict__ pred, const float* __restrict__ gt,
    const float* __restrict__ bwp,  const float* __restrict__ bwg,
    float* __restrict__ minP2G, float* __restrict__ minG2P,
    float* __restrict__ densP,  float* __restrict__ densG)
{
    __shared__ float4 sCol[1536];   // 24 KB: 16 col tiles
    __shared__ float4 sRow[96];     // 1.5 KB: this block's 128 points
    float* sRed = (float*)sCol;     // aliased: end-of-block reduction scratch

    const int tid  = threadIdx.x;
    const int ty   = tid & 15;      // row group (lane bits 0..3)
    const int tx   = tid >> 4;      // col group
    const int wave = tid >> 6;
    const int lane = tid & 63;

    const int bid  = blockIdx.x;
    const int kind = bid % 6;
    const int rem  = bid / 6;       // [0, 256)
    const int b    = rem & 7;
    const int RT   = rem >> 3;      // row tile [0, 32)

    const float* rowsrc; const float* colsrc; float scale;
    if (kind == 0)      { rowsrc = pred; colsrc = gt;   scale = 1.0f; }
    else if (kind == 1) { rowsrc = gt;   colsrc = pred; scale = 1.0f; }
    else if (kind < 4)  { rowsrc = pred; colsrc = pred;
                          const float bw = bwp[0];
                          scale = sqrtf(0.5f/(bw*bw*0.6931471805599453f)); }
    else                { rowsrc = gt;   colsrc = gt;
                          const float bw = bwg[0];
                          scale = sqrtf(0.5f/(bw*bw*0.6931471805599453f)); }

    const float4* rbase = (const float4*)(rowsrc + ((size_t)b*NPTS + RT*TS)*3);
    const float4* cbase = (const float4*)(colsrc + (size_t)b*NPTS*3);

    if (tid < 96) {
        float4 v = rbase[tid];
        v.x *= scale; v.y *= scale; v.z *= scale; v.w *= scale;
        sRow[tid] = v;
    }

    if (kind < 2) {
        // ================= cross: min over 32 col tiles, 2 staging phases ====
        float rx[8], ry[8], rz[8], rr[8], rmin[8];
        #pragma unroll
        for (int r = 0; r < 8; ++r) rmin[r] = BIGF;
        bool gotRows = false;

        for (int ph = 0; ph < 2; ++ph) {
            const float4* src = cbase + ph*1536;
            __syncthreads();                       // sCol reuse guard
            #pragma unroll
            for (int i = 0; i < 6; ++i) sCol[tid + i*TPB] = src[tid + i*TPB];
            __syncthreads();
            if (!gotRows) {
                unpack8(sRow, ty*6, rx, ry, rz);
                #pragma unroll
                for (int r = 0; r < 8; ++r)
                    rr[r] = fmaf(rx[r],rx[r], fmaf(ry[r],ry[r], rz[r]*rz[r]));
                gotRows = true;
            }
            for (int t = 0; t < 16; ++t) {
                float cx[8], cy[8], cz[8];
                unpack8(sCol, t*96 + tx*6, cx, cy, cz);
                #pragma unroll
                for (int c = 0; c < 8; ++c) {
                    const float ax = -2.0f*cx[c], ay = -2.0f*cy[c], az = -2.0f*cz[c];
                    const float cc = fmaf(cx[c],cx[c], fmaf(cy[c],cy[c], cz[c]*cz[c]));
                    #pragma unroll
                    for (int r = 0; r < 8; ++r) {
                        float tv = fmaf(ax, rx[r], cc);
                        tv = fmaf(ay, ry[r], tv);
                        tv = fmaf(az, rz[r], tv);
                        rmin[r] = fminf(rmin[r], tv);   // tracks min(cc - 2rc)
                    }
                }
            }
        }
        // finalize: true d2 = rmin + rr, clamped at 0
        float v[8];
        #pragma unroll
        for (int r = 0; r < 8; ++r) {
            float m = fmaxf(rmin[r] + rr[r], 0.0f);
            m = fminf(m, __shfl_xor(m, 16, 64));
            m = fminf(m, __shfl_xor(m, 32, 64));
            v[r] = m;                                  // wave partial (all lanes)
        }
        __syncthreads();                               // sCol reads done -> sRed
        if (wave > 0 && lane < 16) {
            #pragma unroll
            for (int r = 0; r < 8; ++r) sRed[(wave-1)*128 + lane*8 + r] = v[r];
        }
        __syncthreads();
        if (wave == 0 && lane < 16) {
            float* out = (kind == 0 ? minP2G : minG2P) + b*NPTS + RT*TS + lane*8;
            #pragma unroll
            for (int r = 0; r < 8; ++r) {
                const int o = lane*8 + r;
                out[r] = fminf(fminf(v[r], sRed[o]),
                               fminf(sRed[128 + o], sRed[256 + o]));
            }
        }
    } else {
        // ================= density: sum over 16 col tiles (one half) =========
        const int h = kind & 1;
        float* D = (kind < 4 ? densP : densG) + h*(NB*NPTS);

        const float4* src = cbase + h*1536;
        #pragma unroll
        for (int i = 0; i < 6; ++i) {
            float4 x = src[tid + i*TPB];
            x.x *= scale; x.y *= scale; x.z *= scale; x.w *= scale;
            sCol[tid + i*TPB] = x;
        }
        __syncthreads();

        float rx[8], ry[8], rz[8], nrr[8], racc[8];
        unpack8(sRow, ty*6, rx, ry, rz);
        #pragma unroll
        for (int r = 0; r < 8; ++r) {
            nrr[r]  = -fmaf(rx[r],rx[r], fmaf(ry[r],ry[r], rz[r]*rz[r]));
            racc[r] = 0.0f;
        }

        for (int t = 0; t < 16; ++t) {
            float cx[8], cy[8], cz[8];
            unpack8(sCol, t*96 + tx*6, cx, cy, cz);
            #pragma unroll
            for (int c = 0; c < 8; ++c) {
                const float ax = 2.0f*cx[c], ay = 2.0f*cy[c], az = 2.0f*cz[c];
                const float ncc = fmaf(-cx[c],cx[c], fmaf(-cy[c],cy[c], -cz[c]*cz[c]));
                #pragma unroll
                for (int r = 0; r < 8; ++r) {
                    float e = fmaf(ax, rx[r], ncc);
                    e = fmaf(ay, ry[r], e);
                    e = fmaf(az, rz[r], e);
                    e = e + nrr[r];                    // e = -(scaled d^2) <= ~0
                    racc[r] += __builtin_amdgcn_exp2f(e);
                }
            }
        }
        // reduce-add over tx, store per-half partial (exclusive ownership)
        float v[8];
        #pragma unroll
        for (int r = 0; r < 8; ++r) {
            float s = racc[r];
            s += __shfl_xor(s, 16, 64);
            s += __shfl_xor(s, 32, 64);
            v[r] = s;
        }
        __syncthreads();
        if (wave > 0 && lane < 16) {
            #pragma unroll
            for (int r = 0; r < 8; ++r) sRed[(wave-1)*128 + lane*8 + r] = v[r];
        }
        __syncthreads();
        if (wave == 0 && lane < 16) {
            float* out = D + b*NPTS + RT*TS + lane*8;
            #pragma unroll
            for (int r = 0; r < 8; ++r) {
                const int o = lane*8 + r;
                out[r] = (v[r] + sRed[o]) + (sRed[128 + o] + sRed[256 + o]);
            }
        }
    }
}

__global__ __launch_bounds__(256) void dacl_combine(
    const float* __restrict__ minP2G, const float* __restrict__ minG2P,
    const float* __restrict__ densP, const float* __restrict__ densG,
    float* __restrict__ bsum)
{
    const int g   = blockIdx.x * 256 + threadIdx.x;  // [0, 65536)
    const int dir = g >> 15;
    const int idx = g & 32767;
    const float m  = dir ? minG2P[idx] : minP2G[idx];
    const float dn = dir ? (densG[idx] + densG[idx + NB*NPTS])
                         : (densP[idx] + densP[idx + NB*NPTS]);
    float val = m / (dn * (1.0f/4095.0f) + 1e-6f) * (1.0f/32768.0f);

    #pragma unroll
    for (int off = 32; off; off >>= 1) val += __shfl_down(val, off);
    __shared__ float sm[4];
    const int lane = threadIdx.x & 63, wid = threadIdx.x >> 6;
    if (lane == 0) sm[wid] = val;
    __syncthreads();
    if (threadIdx.x == 0) bsum[blockIdx.x] = (sm[0] + sm[1]) + (sm[2] + sm[3]);
}

__global__ __launch_bounds__(256) void dacl_final(
    const float* __restrict__ bsum, float* __restrict__ out)
{
    float v = bsum[threadIdx.x];
    #pragma unroll
    for (int off = 32; off; off >>= 1) v += __shfl_down(v, off);
    __shared__ float sm[4];
    const int lane = threadIdx.x & 63, wid = threadIdx.x >> 6;
    if (lane == 0) sm[wid] = v;
    __syncthreads();
    if (threadIdx.x == 0) out[0] = (sm[0] + sm[1]) + (sm[2] + sm[3]);
}

extern "C" void kernel_launch(void* const* d_in, const int* in_sizes, int n_in,
                              void* d_out, int out_size, void* d_ws, size_t ws_size,
                              hipStream_t stream)
{
    const float* pred = (const float*)d_in[0];
    const float* gt   = (const float*)d_in[1];
    const float* bwp  = (const float*)d_in[2];
    const float* bwg  = (const float*)d_in[3];

    float* minP2G = (float*)d_ws;                 // [NB*NPTS]
    float* minG2P = minP2G + NB*NPTS;             // [NB*NPTS]
    float* densP  = minG2P + NB*NPTS;             // [2][NB*NPTS]
    float* densG  = densP + 2*NB*NPTS;            // [2][NB*NPTS]
    float* bsum   = densG + 2*NB*NPTS;            // [256]

    dacl_pairs<<<1536, TPB, 0, stream>>>(pred, gt, bwp, bwg,
                                         minP2G, minG2P, densP, densG);
    dacl_combine<<<(2*NB*NPTS)/256, 256, 0, stream>>>(minP2G, minG2P, densP, densG, bsum);
    dacl_final<<<1, 256, 0, stream>>>(bsum, (float*)d_out);
}